// Round 3
// baseline (355.340 us; speedup 1.0000x reference)
//
#include <hip/hip_runtime.h>
#include <stdint.h>

typedef __bf16 bf16;
typedef __bf16 bf16x4 __attribute__((ext_vector_type(4)));
typedef __bf16 bf16x8 __attribute__((ext_vector_type(8)));
typedef float  f32x4  __attribute__((ext_vector_type(4)));

#define MFMA16(A, B, C) __builtin_amdgcn_mfma_f32_16x16x32_bf16((A), (B), (C), 0, 0, 0)

// B=960 windows, N=144, DIM=192, HEADS=6, hd=32, TYPES=64, n_mask=15
// ws layout (bytes):
//   wqkvt [576][192] bf16 @ 0            (221184)
//   woutt [192][192] bf16 @ 221184       (73728)   ends 294912
//   bias  [384][144][144] bf16 @ 294912  (15925248) ends 16220160
//   xb    [138240][192] bf16 @ 16220160  (53084160) ends 69304320   } aliased:
//   obuf  = same region (xb dead after k_qkv, obuf written by k_attn)
//   qb    [960][6][144][32] bf16 @ 69304320  ends 122388480
//   kb    same @ 122388480 ends 175472640
//   vtb   [960][6][32][144] @ 175472640 ends 228556800  (~218 MiB)

// ---------------- weight transpose + bf16 cast ----------------
__global__ __launch_bounds__(256) void k_prep(const float* __restrict__ wqkv,
                                              const float* __restrict__ wout,
                                              bf16* __restrict__ wqkvt,
                                              bf16* __restrict__ woutt) {
    int i = blockIdx.x * 256 + threadIdx.x;   // 576 blocks
    if (i < 576 * 192) {
        int n = i / 192, k = i - n * 192;
        wqkvt[i] = (bf16)wqkv[k * 576 + n];   // [n][k], k-contiguous
    } else {
        int j = i - 576 * 192;
        int n = j / 192, k = j - n * 192;
        woutt[j] = (bf16)wout[k * 192 + n];
    }
}

// ---------------- x -> bf16 ----------------
__global__ __launch_bounds__(256) void k_xcvt(const float* __restrict__ x,
                                              bf16* __restrict__ xb) {
    int i = blockIdx.x * 256 + threadIdx.x;   // 12960 blocks: i < 3317760 exactly
    f32x4 a = *reinterpret_cast<const f32x4*>(x + (size_t)i * 8);
    f32x4 b = *reinterpret_cast<const f32x4*>(x + (size_t)i * 8 + 4);
    bf16x8 v;
    v[0] = (bf16)a[0]; v[1] = (bf16)a[1]; v[2] = (bf16)a[2]; v[3] = (bf16)a[3];
    v[4] = (bf16)b[0]; v[5] = (bf16)b[1]; v[6] = (bf16)b[2]; v[7] = (bf16)b[3];
    *reinterpret_cast<bf16x8*>(xb + (size_t)i * 8) = v;
}

// ---------------- earth-bias materialization ----------------
__global__ __launch_bounds__(256) void k_bias(const float* __restrict__ btab,
                                              bf16* __restrict__ bias) {
    __shared__ float tb[3312];
    const int th = blockIdx.x;                 // t*6 + h
    for (int i = threadIdx.x; i < 3312; i += 256)
        tb[i] = btab[(size_t)i * 384 + th];
    __syncthreads();
    bf16* op = bias + (size_t)th * 20736;
    for (int o = threadIdx.x; o < 20736; o += 256) {
        int n = o / 144, m = o - n * 144;
        int zn = n / 72, rn = n - zn * 72, hn = rn / 12, wn = rn - hn * 12;
        int zm = m / 72, rm = m - zm * 72, hm = rm / 12, wm = rm - hm * 12;
        int idx = 828 * (zn + 2 * zm) + 23 * (hn + 6 * hm) + (wn - wm + 11);
        op[o] = (bf16)tb[idx];
    }
}

// ---------------- QKV projection: stationary-W, no LDS, no barriers ----------------
// grid 540 x 576 threads (9 waves). Wave w owns cols [w*64, w*64+64) (entirely q, k or v).
// Block handles 256 rows = 16 tiles of 16 (tiles never cross the 144-row window boundary).
__global__ __launch_bounds__(576) void k_qkv(const bf16* __restrict__ xb,
                                             const float* __restrict__ bqkv,
                                             const bf16* __restrict__ wt,
                                             bf16* __restrict__ qb,
                                             bf16* __restrict__ kb,
                                             bf16* __restrict__ vtb) {
    const int tid = threadIdx.x;
    const int lane = tid & 63;
    const int w = tid >> 6;
    const int l15 = lane & 15;
    const int g = lane >> 4;
    const int c0 = w * 64;

    // stationary A fragments: 4 strips x 6 ksteps (96 VGPR)
    bf16x8 a[4][6];
    #pragma unroll
    for (int s = 0; s < 4; ++s)
        #pragma unroll
        for (int ks = 0; ks < 6; ++ks)
            a[s][ks] = *reinterpret_cast<const bf16x8*>(wt + (size_t)(c0 + s * 16 + l15) * 192 + ks * 32 + g * 8);

    // per-strip metadata (wave-uniform except d0 via g)
    const int qi = c0 / 192;                   // 0=q 1=k 2=v, uniform per wave
    const float scale = (qi == 0) ? 0.17677669529663687f : 1.0f;
    int hs[4], d0s[4];
    f32x4 bv[4];
    #pragma unroll
    for (int s = 0; s < 4; ++s) {
        int cbase = c0 + s * 16;
        int rem = cbase - qi * 192;
        hs[s] = rem >> 5;
        d0s[s] = (rem & 31) + g * 4;
        bv[s] = *reinterpret_cast<const f32x4*>(bqkv + cbase + g * 4);
    }
    bf16* qkbase = (qi == 0) ? qb : kb;

    const size_t row_base = (size_t)blockIdx.x * 256;
    for (int t = 0; t < 16; ++t) {
        const int row0 = (int)row_base + t * 16;
        const bf16* xrow = xb + (size_t)(row0 + l15) * 192 + g * 8;
        bf16x8 bfr[6];
        #pragma unroll
        for (int ks = 0; ks < 6; ++ks)
            bfr[ks] = *reinterpret_cast<const bf16x8*>(xrow + ks * 32);
        f32x4 acc[4];
        #pragma unroll
        for (int s = 0; s < 4; ++s) acc[s] = (f32x4){0.f, 0.f, 0.f, 0.f};
        #pragma unroll
        for (int ks = 0; ks < 6; ++ks)
            #pragma unroll
            for (int s = 0; s < 4; ++s)
                acc[s] = MFMA16(a[s][ks], bfr[ks], acc[s]);

        // D: row(g*4+r) = output col c, col(l15) = x-row
        const int bidx = row0 / 144;
        const int n = row0 - bidx * 144 + l15;
        #pragma unroll
        for (int s = 0; s < 4; ++s) {
            float v0 = (acc[s][0] + bv[s][0]) * scale;
            float v1 = (acc[s][1] + bv[s][1]) * scale;
            float v2 = (acc[s][2] + bv[s][2]) * scale;
            float v3 = (acc[s][3] + bv[s][3]) * scale;
            if (qi == 2) {
                bf16* dst = vtb + ((size_t)(bidx * 6 + hs[s]) * 32 + d0s[s]) * 144 + n;
                dst[0]   = (bf16)v0;
                dst[144] = (bf16)v1;
                dst[288] = (bf16)v2;
                dst[432] = (bf16)v3;
            } else {
                bf16x4 sv;
                sv[0] = (bf16)v0; sv[1] = (bf16)v1; sv[2] = (bf16)v2; sv[3] = (bf16)v3;
                *reinterpret_cast<bf16x4*>(qkbase + ((size_t)(bidx * 6 + hs[s]) * 144 + n) * 32 + d0s[s]) = sv;
            }
        }
    }
}

// ---------------- windowed attention (swapped QK^T, 48-row chunks) ----------------
// grid 17280: hb = bid%5760 -> (b,h); chunk = bid/5760 (rows [48c,48c+48)); 192 thr = 3 waves.
__global__ __launch_bounds__(192) void k_attn(const bf16* __restrict__ qb,
                                              const bf16* __restrict__ kb,
                                              const bf16* __restrict__ vtb,
                                              const float* __restrict__ mask,
                                              const bf16* __restrict__ bias,
                                              bf16* __restrict__ ob) {
    __shared__ bf16 pl[48][168];   // P rows (n local); m padded 144->160 zeros; stride 168
    const int bid = blockIdx.x;
    const int hb = bid % 5760;
    const int chunk = bid / 5760;
    const int b = hb / 6;
    const int h = hb - b * 6;
    const int t = b & 63;
    const int wm = b % 15;
    const int tid = threadIdx.x;
    const int lane = tid & 63;
    const int wv = tid >> 6;       // 0..2
    const int l15 = lane & 15;
    const int g = lane >> 4;

    const bf16* qp = qb + (size_t)hb * 4608;
    const bf16* kp = kb + (size_t)hb * 4608;
    const bf16* vp = vtb + (size_t)hb * 4608;

    // zero the m-pad cols [144,160) of this wave's 16 rows
    if (lane < 32) {
        bf16x8 z;
        #pragma unroll
        for (int i = 0; i < 8; ++i) z[i] = (bf16)0.f;
        *reinterpret_cast<bf16x8*>(&pl[wv * 16 + (lane >> 1)][144 + (lane & 1) * 8]) = z;
    }

    const int nloc = wv * 16 + l15;            // local n-row (this thread's softmax row)
    const int n = chunk * 48 + nloc;           // global n

    // ---- S^T = K·Q^T : A=K (i=m), B=Q (j=n). D: row(g*4+r)=m within tile, col(l15)=n ----
    bf16x8 bq = *reinterpret_cast<const bf16x8*>(qp + (size_t)n * 32 + g * 8);
    f32x4 s[9];
    #pragma unroll
    for (int ct = 0; ct < 9; ++ct) {
        bf16x8 ak = *reinterpret_cast<const bf16x8*>(kp + (size_t)(ct * 16 + l15) * 32 + g * 8);
        f32x4 z = (f32x4){0.f, 0.f, 0.f, 0.f};
        s[ct] = MFMA16(ak, bq, z);
    }

    // ---- + bias + mask (vectorized: thread owns row n, m = 16ct+4g+{0..3}) ----
    const float* mrow = mask + (size_t)wm * 20736 + (size_t)n * 144;
    const bf16* brow = bias + (size_t)(t * 6 + h) * 20736 + (size_t)n * 144;
    float rmax = -3.0e38f;
    #pragma unroll
    for (int ct = 0; ct < 9; ++ct) {
        int moff = ct * 16 + g * 4;
        f32x4 mv = *reinterpret_cast<const f32x4*>(mrow + moff);
        bf16x4 bvv = *reinterpret_cast<const bf16x4*>(brow + moff);
        #pragma unroll
        for (int r = 0; r < 4; ++r) {
            float v = s[ct][r] + (float)bvv[r] + mv[r];
            s[ct][r] = v;
            rmax = fmaxf(rmax, v);
        }
    }
    rmax = fmaxf(rmax, __shfl_xor(rmax, 16));
    rmax = fmaxf(rmax, __shfl_xor(rmax, 32));
    float rsum = 0.f;
    #pragma unroll
    for (int ct = 0; ct < 9; ++ct) {
        #pragma unroll
        for (int r = 0; r < 4; ++r) {
            float e = __expf(s[ct][r] - rmax);
            s[ct][r] = e;
            rsum += e;
        }
    }
    rsum += __shfl_xor(rsum, 16);
    rsum += __shfl_xor(rsum, 32);
    const float rinv = 1.0f / rsum;

    // P^T in regs -> write P[n][m] to LDS (wave-local rows)
    #pragma unroll
    for (int ct = 0; ct < 9; ++ct) {
        #pragma unroll
        for (int r = 0; r < 4; ++r)
            pl[nloc][ct * 16 + g * 4 + r] = (bf16)(s[ct][r] * rinv);
    }
    __asm__ __volatile__("s_waitcnt lgkmcnt(0)" ::: "memory");  // same-wave write->read

    // ---- P @ V (5 K-steps over padded m=160). A=P rows n, B=V^T rows d ----
    f32x4 o0 = (f32x4){0.f, 0.f, 0.f, 0.f};
    f32x4 o1 = (f32x4){0.f, 0.f, 0.f, 0.f};
    #pragma unroll
    for (int mc = 0; mc < 5; ++mc) {
        bf16x8 pa = *reinterpret_cast<const bf16x8*>(&pl[wv * 16 + l15][mc * 32 + g * 8]);
        bf16x8 v0 = *reinterpret_cast<const bf16x8*>(vp + (size_t)(0  + l15) * 144 + mc * 32 + g * 8);
        bf16x8 v1 = *reinterpret_cast<const bf16x8*>(vp + (size_t)(16 + l15) * 144 + mc * 32 + g * 8);
        o0 = MFMA16(pa, v0, o0);
        o1 = MFMA16(pa, v1, o1);
    }
    // D: row(g*4+r) = n (local), col(l15) = d
    bf16* op = ob + (size_t)b * 27648 + h * 32;
    #pragma unroll
    for (int r = 0; r < 4; ++r) {
        int nn = chunk * 48 + wv * 16 + g * 4 + r;
        op[(size_t)nn * 192 + l15]      = (bf16)o0[r];
        op[(size_t)nn * 192 + 16 + l15] = (bf16)o1[r];
    }
}

// ---------------- output projection: stationary-W, no LDS ----------------
// grid 540 x 768 threads (12 waves): wave = (cs = w%3 col-strip of 64, rq = w/3 row-quarter)
__global__ __launch_bounds__(768) void k_out(const bf16* __restrict__ ob,
                                             const bf16* __restrict__ wt,
                                             const float* __restrict__ bout,
                                             float* __restrict__ out) {
    const int tid = threadIdx.x;
    const int lane = tid & 63;
    const int w = tid >> 6;
    const int cs = w % 3;
    const int rq = w / 3;
    const int l15 = lane & 15;
    const int g = lane >> 4;
    const int c0 = cs * 64;

    bf16x8 a[4][6];
    #pragma unroll
    for (int s = 0; s < 4; ++s)
        #pragma unroll
        for (int ks = 0; ks < 6; ++ks)
            a[s][ks] = *reinterpret_cast<const bf16x8*>(wt + (size_t)(c0 + s * 16 + l15) * 192 + ks * 32 + g * 8);
    f32x4 bv[4];
    #pragma unroll
    for (int s = 0; s < 4; ++s)
        bv[s] = *reinterpret_cast<const f32x4*>(bout + c0 + s * 16 + g * 4);

    for (int t = rq * 4; t < rq * 4 + 4; ++t) {
        const int row0 = blockIdx.x * 256 + t * 16;
        const bf16* orow = ob + (size_t)(row0 + l15) * 192 + g * 8;
        bf16x8 bfr[6];
        #pragma unroll
        for (int ks = 0; ks < 6; ++ks)
            bfr[ks] = *reinterpret_cast<const bf16x8*>(orow + ks * 32);
        f32x4 acc[4];
        #pragma unroll
        for (int s = 0; s < 4; ++s) acc[s] = (f32x4){0.f, 0.f, 0.f, 0.f};
        #pragma unroll
        for (int ks = 0; ks < 6; ++ks)
            #pragma unroll
            for (int s = 0; s < 4; ++s)
                acc[s] = MFMA16(a[s][ks], bfr[ks], acc[s]);
        // D: row(g*4+r) = col c, col(l15) = row n -> f32x4 store of 4 consecutive c
        const int n = row0 + l15;
        #pragma unroll
        for (int s = 0; s < 4; ++s) {
            f32x4 v;
            v[0] = acc[s][0] + bv[s][0];
            v[1] = acc[s][1] + bv[s][1];
            v[2] = acc[s][2] + bv[s][2];
            v[3] = acc[s][3] + bv[s][3];
            *reinterpret_cast<f32x4*>(out + (size_t)n * 192 + c0 + s * 16 + g * 4) = v;
        }
    }
}

extern "C" void kernel_launch(void* const* d_in, const int* in_sizes, int n_in,
                              void* d_out, int out_size, void* d_ws, size_t ws_size,
                              hipStream_t stream) {
    const float* x    = (const float*)d_in[0];
    const float* mask = (const float*)d_in[1];
    const float* wqkv = (const float*)d_in[2];
    const float* bqkv = (const float*)d_in[3];
    const float* wout = (const float*)d_in[4];
    const float* bout = (const float*)d_in[5];
    const float* btab = (const float*)d_in[6];
    float* out = (float*)d_out;

    char* ws = (char*)d_ws;
    bf16* wqkvt = (bf16*)(ws);
    bf16* woutt = (bf16*)(ws + 221184);
    bf16* bias  = (bf16*)(ws + 294912);
    bf16* xb    = (bf16*)(ws + 16220160);
    bf16* obuf  = xb;                       // alias: xb dead after k_qkv
    bf16* qb    = (bf16*)(ws + 69304320);
    bf16* kb    = (bf16*)(ws + 122388480);
    bf16* vtb   = (bf16*)(ws + 175472640);  // ends 228556800 (~218 MiB)

    hipLaunchKernelGGL(k_prep, dim3(576),   dim3(256), 0, stream, wqkv, wout, wqkvt, woutt);
    hipLaunchKernelGGL(k_xcvt, dim3(12960), dim3(256), 0, stream, x, xb);
    hipLaunchKernelGGL(k_bias, dim3(384),   dim3(256), 0, stream, btab, bias);
    hipLaunchKernelGGL(k_qkv,  dim3(540),   dim3(576), 0, stream, xb, bqkv, wqkvt, qb, kb, vtb);
    hipLaunchKernelGGL(k_attn, dim3(17280), dim3(192), 0, stream, qb, kb, vtb, mask, bias, obuf);
    hipLaunchKernelGGL(k_out,  dim3(540),   dim3(768), 0, stream, obuf, woutt, bout, out);
}